// Round 1
// baseline (5767.001 us; speedup 1.0000x reference)
//
#include <hip/hip_runtime.h>
#include <stdint.h>

#define N_NODES 50000
#define N_EDGES 1600000
#define IN_DIM  128
#define OUT_DIM 64
#define HEADS   4
#define HO      (HEADS*OUT_DIM)   // 256

// ---------- helpers ----------
__device__ __forceinline__ unsigned fenc(float f) {
    unsigned u = __float_as_uint(f);
    return (u & 0x80000000u) ? ~u : (u | 0x80000000u);
}
__device__ __forceinline__ float fdec(unsigned u) {
    return __uint_as_float((u & 0x80000000u) ? (u ^ 0x80000000u) : ~u);
}
__device__ __forceinline__ float lrelu(float v) {
    return v >= 0.f ? v : 0.01f * v;
}

// ---------- kernel A: h = x @ W  (per head), plus per-node scores ----------
// s_src[n,h] = dot(h[n,h,:], a[h,:64]),  s_dst[n,h] = dot(h[n,h,:], a[h,64:])
#define NPW 8            // nodes per wave
#define WPB 4            // waves per block
#define NPB (NPW*WPB)    // 32 nodes per block

__global__ __launch_bounds__(256) void k_gemm(
    const float* __restrict__ x, const float* __restrict__ W,
    const float* __restrict__ a,
    float* __restrict__ h, float* __restrict__ s_src, float* __restrict__ s_dst)
{
    __shared__ float xs[NPB][IN_DIM];   // 32*128*4 = 16 KB
    const int tid  = threadIdx.x;
    const int wave = tid >> 6;
    const int lane = tid & 63;
    const int node0 = blockIdx.x * NPB;

    // stage x rows into LDS (vectorized, guarded)
    {
        float4* xsv = (float4*)&xs[0][0];
        const int ROW4 = IN_DIM / 4;            // 32
        const int total4 = NPB * ROW4;          // 1024
        for (int i = tid; i < total4; i += 256) {
            int row  = i / ROW4;
            int node = node0 + row;
            float4 v = make_float4(0.f, 0.f, 0.f, 0.f);
            if (node < N_NODES)
                v = ((const float4*)x)[(size_t)node * ROW4 + (i % ROW4)];
            xsv[i] = v;
        }
    }
    __syncthreads();

    const int head = lane >> 4;          // 0..3
    const int og   = (lane & 15) * 4;    // 0,4,...,60
    const int wn0  = wave * NPW;

    float4 acc[NPW];
    #pragma unroll
    for (int i = 0; i < NPW; ++i) acc[i] = make_float4(0.f, 0.f, 0.f, 0.f);

    const float* wp = &W[(size_t)(head * IN_DIM) * OUT_DIM + og];
    #pragma unroll 4
    for (int k = 0; k < IN_DIM; ++k) {
        float4 w4 = *(const float4*)(wp + (size_t)k * OUT_DIM);
        #pragma unroll
        for (int i = 0; i < NPW; ++i) {
            float xv = xs[wn0 + i][k];
            acc[i].x = fmaf(xv, w4.x, acc[i].x);
            acc[i].y = fmaf(xv, w4.y, acc[i].y);
            acc[i].z = fmaf(xv, w4.z, acc[i].z);
            acc[i].w = fmaf(xv, w4.w, acc[i].w);
        }
    }

    const float4 as = *(const float4*)&a[head * (2*OUT_DIM) + og];
    const float4 ad = *(const float4*)&a[head * (2*OUT_DIM) + OUT_DIM + og];

    #pragma unroll
    for (int i = 0; i < NPW; ++i) {
        int node = node0 + wn0 + i;
        if (node >= N_NODES) continue;   // wave-uniform
        *(float4*)&h[(size_t)node * HO + head * OUT_DIM + og] = acc[i];
        float ps = acc[i].x*as.x + acc[i].y*as.y + acc[i].z*as.z + acc[i].w*as.w;
        float pd = acc[i].x*ad.x + acc[i].y*ad.y + acc[i].z*ad.z + acc[i].w*ad.w;
        #pragma unroll
        for (int m = 8; m >= 1; m >>= 1) {
            ps += __shfl_xor(ps, m, 16);
            pd += __shfl_xor(pd, m, 16);
        }
        if ((lane & 15) == 0) {
            s_src[node * HEADS + head] = ps;
            s_dst[node * HEADS + head] = pd;
        }
    }
}

// ---------- kernel B: global per-head max of leaky_relu(s_src[src]+s_dst[dst]) ----------
__global__ __launch_bounds__(256) void k_max(
    const int* __restrict__ esrc, const int* __restrict__ edst,
    const float* __restrict__ s_src, const float* __restrict__ s_dst,
    unsigned* __restrict__ gmax)
{
    float m0 = -1e30f, m1 = -1e30f, m2 = -1e30f, m3 = -1e30f;
    const int stride = gridDim.x * blockDim.x;
    for (int e = blockIdx.x * blockDim.x + threadIdx.x; e < N_EDGES; e += stride) {
        int s = esrc[e], d = edst[e];
        float4 ss = *(const float4*)&s_src[s * HEADS];
        float4 sd = *(const float4*)&s_dst[d * HEADS];
        m0 = fmaxf(m0, lrelu(ss.x + sd.x));
        m1 = fmaxf(m1, lrelu(ss.y + sd.y));
        m2 = fmaxf(m2, lrelu(ss.z + sd.z));
        m3 = fmaxf(m3, lrelu(ss.w + sd.w));
    }
    #pragma unroll
    for (int m = 32; m >= 1; m >>= 1) {
        m0 = fmaxf(m0, __shfl_xor(m0, m));
        m1 = fmaxf(m1, __shfl_xor(m1, m));
        m2 = fmaxf(m2, __shfl_xor(m2, m));
        m3 = fmaxf(m3, __shfl_xor(m3, m));
    }
    if ((threadIdx.x & 63) == 0) {
        atomicMax(&gmax[0], fenc(m0));
        atomicMax(&gmax[1], fenc(m1));
        atomicMax(&gmax[2], fenc(m2));
        atomicMax(&gmax[3], fenc(m3));
    }
}

// ---------- kernel C: per-head sum of exp(e - max), fp64 accumulation ----------
__global__ __launch_bounds__(256) void k_sum(
    const int* __restrict__ esrc, const int* __restrict__ edst,
    const float* __restrict__ s_src, const float* __restrict__ s_dst,
    const unsigned* __restrict__ gmax, double* __restrict__ gsum)
{
    const float mx0 = fdec(gmax[0]);
    const float mx1 = fdec(gmax[1]);
    const float mx2 = fdec(gmax[2]);
    const float mx3 = fdec(gmax[3]);
    double a0 = 0.0, a1 = 0.0, a2 = 0.0, a3 = 0.0;
    const int stride = gridDim.x * blockDim.x;
    for (int e = blockIdx.x * blockDim.x + threadIdx.x; e < N_EDGES; e += stride) {
        int s = esrc[e], d = edst[e];
        float4 ss = *(const float4*)&s_src[s * HEADS];
        float4 sd = *(const float4*)&s_dst[d * HEADS];
        a0 += (double)expf(lrelu(ss.x + sd.x) - mx0);
        a1 += (double)expf(lrelu(ss.y + sd.y) - mx1);
        a2 += (double)expf(lrelu(ss.z + sd.z) - mx2);
        a3 += (double)expf(lrelu(ss.w + sd.w) - mx3);
    }
    #pragma unroll
    for (int m = 32; m >= 1; m >>= 1) {
        a0 += __shfl_xor(a0, m);
        a1 += __shfl_xor(a1, m);
        a2 += __shfl_xor(a2, m);
        a3 += __shfl_xor(a3, m);
    }
    if ((threadIdx.x & 63) == 0) {
        atomicAdd(&gsum[0], a0);
        atomicAdd(&gsum[1], a1);
        atomicAdd(&gsum[2], a2);
        atomicAdd(&gsum[3], a3);
    }
}

// ---------- kernel D: out[dst] += alpha * h[src]  (one wave per edge) ----------
__global__ __launch_bounds__(256) void k_scatter(
    const int* __restrict__ esrc, const int* __restrict__ edst,
    const float* __restrict__ h,
    const float* __restrict__ s_src, const float* __restrict__ s_dst,
    const unsigned* __restrict__ gmax, const double* __restrict__ gsum,
    float* __restrict__ out)
{
    const int gw = (int)((blockIdx.x * 256u + threadIdx.x) >> 6);  // edge id
    if (gw >= N_EDGES) return;
    const int lane = threadIdx.x & 63;
    const int head = lane >> 4;
    const int og   = (lane & 15) * 4;

    const int s = esrc[gw];
    const int d = edst[gw];
    const float ev  = lrelu(s_src[s * HEADS + head] + s_dst[d * HEADS + head]);
    const float mx  = fdec(gmax[head]);
    const float inv = (float)(1.0 / gsum[head]);
    const float alpha = expf(ev - mx) * inv;

    const float4 hv = *(const float4*)&h[(size_t)s * HO + head * OUT_DIM + og];
    float* op = &out[(size_t)d * HO + head * OUT_DIM + og];
    atomicAdd(op + 0, alpha * hv.x);
    atomicAdd(op + 1, alpha * hv.y);
    atomicAdd(op + 2, alpha * hv.z);
    atomicAdd(op + 3, alpha * hv.w);
}

// ---------- launch ----------
extern "C" void kernel_launch(void* const* d_in, const int* in_sizes, int n_in,
                              void* d_out, int out_size, void* d_ws, size_t ws_size,
                              hipStream_t stream)
{
    const float* x    = (const float*)d_in[0];
    const int*   eidx = (const int*)d_in[1];   // jax downgrades int64->int32 (x64 off)
    const float* W    = (const float*)d_in[2];
    const float* a    = (const float*)d_in[3];
    float* out = (float*)d_out;

    // workspace layout
    float*    h     = (float*)d_ws;                          // 12.8M floats (51.2 MB)
    float*    s_src = h + (size_t)N_NODES * HO;              // 200K floats
    float*    s_dst = s_src + (size_t)N_NODES * HEADS;       // 200K floats
    unsigned* gmax  = (unsigned*)(s_dst + (size_t)N_NODES * HEADS);
    double*   gsum  = (double*)(gmax + 4);                   // 8B-aligned (52,800,016)

    const int* esrc = eidx;
    const int* edst = eidx + N_EDGES;

    hipMemsetAsync(d_out, 0, (size_t)out_size * sizeof(float), stream);
    hipMemsetAsync(gmax, 0, 4 * sizeof(unsigned) + 4 * sizeof(double), stream);

    k_gemm<<<(N_NODES + NPB - 1) / NPB, 256, 0, stream>>>(x, W, a, h, s_src, s_dst);
    k_max<<<1024, 256, 0, stream>>>(esrc, edst, s_src, s_dst, gmax);
    k_sum<<<1024, 256, 0, stream>>>(esrc, edst, s_src, s_dst, gmax, gsum);
    k_scatter<<<N_EDGES * 64 / 256, 256, 0, stream>>>(esrc, edst, h, s_src, s_dst,
                                                      gmax, gsum, out);
}

// Round 2
// 919.012 us; speedup vs baseline: 6.2752x; 6.2752x over previous
//
#include <hip/hip_runtime.h>
#include <stdint.h>

#define N_NODES 50000
#define N_EDGES 1600000
#define IN_DIM  128
#define OUT_DIM 64
#define HEADS   4
#define HO      (HEADS*OUT_DIM)   // 256

// ---------- helpers ----------
__device__ __forceinline__ unsigned fenc(float f) {
    unsigned u = __float_as_uint(f);
    return (u & 0x80000000u) ? ~u : (u | 0x80000000u);
}
__device__ __forceinline__ float fdec(unsigned u) {
    return __uint_as_float((u & 0x80000000u) ? (u ^ 0x80000000u) : ~u);
}
__device__ __forceinline__ float lrelu(float v) {
    return v >= 0.f ? v : 0.01f * v;
}

// ---------- kernel A: h = x @ W (per head), plus per-node scores ----------
#define NPW 8            // nodes per wave
#define WPB 4            // waves per block
#define NPB (NPW*WPB)    // 32 nodes per block

__global__ __launch_bounds__(256) void k_gemm(
    const float* __restrict__ x, const float* __restrict__ W,
    const float* __restrict__ a,
    float* __restrict__ h, float* __restrict__ s_src, float* __restrict__ s_dst)
{
    __shared__ float xs[NPB][IN_DIM];   // 16 KB
    const int tid  = threadIdx.x;
    const int wave = tid >> 6;
    const int lane = tid & 63;
    const int node0 = blockIdx.x * NPB;

    {
        float4* xsv = (float4*)&xs[0][0];
        const int ROW4 = IN_DIM / 4;            // 32
        const int total4 = NPB * ROW4;          // 1024
        for (int i = tid; i < total4; i += 256) {
            int row  = i / ROW4;
            int node = node0 + row;
            float4 v = make_float4(0.f, 0.f, 0.f, 0.f);
            if (node < N_NODES)
                v = ((const float4*)x)[(size_t)node * ROW4 + (i % ROW4)];
            xsv[i] = v;
        }
    }
    __syncthreads();

    const int head = lane >> 4;          // 0..3
    const int og   = (lane & 15) * 4;    // 0..60
    const int wn0  = wave * NPW;

    float4 acc[NPW];
    #pragma unroll
    for (int i = 0; i < NPW; ++i) acc[i] = make_float4(0.f, 0.f, 0.f, 0.f);

    const float* wp = &W[(size_t)(head * IN_DIM) * OUT_DIM + og];
    #pragma unroll 4
    for (int k = 0; k < IN_DIM; ++k) {
        float4 w4 = *(const float4*)(wp + (size_t)k * OUT_DIM);
        #pragma unroll
        for (int i = 0; i < NPW; ++i) {
            float xv = xs[wn0 + i][k];
            acc[i].x = fmaf(xv, w4.x, acc[i].x);
            acc[i].y = fmaf(xv, w4.y, acc[i].y);
            acc[i].z = fmaf(xv, w4.z, acc[i].z);
            acc[i].w = fmaf(xv, w4.w, acc[i].w);
        }
    }

    const float4 as = *(const float4*)&a[head * (2*OUT_DIM) + og];
    const float4 ad = *(const float4*)&a[head * (2*OUT_DIM) + OUT_DIM + og];

    #pragma unroll
    for (int i = 0; i < NPW; ++i) {
        int node = node0 + wn0 + i;
        if (node >= N_NODES) continue;
        *(float4*)&h[(size_t)node * HO + head * OUT_DIM + og] = acc[i];
        float ps = acc[i].x*as.x + acc[i].y*as.y + acc[i].z*as.z + acc[i].w*as.w;
        float pd = acc[i].x*ad.x + acc[i].y*ad.y + acc[i].z*ad.z + acc[i].w*ad.w;
        #pragma unroll
        for (int m = 8; m >= 1; m >>= 1) {
            ps += __shfl_xor(ps, m, 16);
            pd += __shfl_xor(pd, m, 16);
        }
        if ((lane & 15) == 0) {
            s_src[node * HEADS + head] = ps;
            s_dst[node * HEADS + head] = pd;
        }
    }
}

// ---------- kernel B: per-head global max + dst histogram ----------
__global__ __launch_bounds__(256) void k_max_hist(
    const int* __restrict__ esrc, const int* __restrict__ edst,
    const float* __restrict__ s_src, const float* __restrict__ s_dst,
    unsigned* __restrict__ gmax, int* __restrict__ cnt)
{
    float m0 = -1e30f, m1 = -1e30f, m2 = -1e30f, m3 = -1e30f;
    const int stride = gridDim.x * blockDim.x;
    for (int e = blockIdx.x * blockDim.x + threadIdx.x; e < N_EDGES; e += stride) {
        int s = esrc[e], d = edst[e];
        atomicAdd(&cnt[d], 1);
        float4 ss = *(const float4*)&s_src[s * HEADS];
        float4 sd = *(const float4*)&s_dst[d * HEADS];
        m0 = fmaxf(m0, lrelu(ss.x + sd.x));
        m1 = fmaxf(m1, lrelu(ss.y + sd.y));
        m2 = fmaxf(m2, lrelu(ss.z + sd.z));
        m3 = fmaxf(m3, lrelu(ss.w + sd.w));
    }
    #pragma unroll
    for (int m = 32; m >= 1; m >>= 1) {
        m0 = fmaxf(m0, __shfl_xor(m0, m));
        m1 = fmaxf(m1, __shfl_xor(m1, m));
        m2 = fmaxf(m2, __shfl_xor(m2, m));
        m3 = fmaxf(m3, __shfl_xor(m3, m));
    }
    if ((threadIdx.x & 63) == 0) {
        atomicMax(&gmax[0], fenc(m0));
        atomicMax(&gmax[1], fenc(m1));
        atomicMax(&gmax[2], fenc(m2));
        atomicMax(&gmax[3], fenc(m3));
    }
}

// ---------- kernel C: one-block exclusive scan of cnt -> row_start; zero cnt ----------
__global__ __launch_bounds__(1024) void k_scan(
    int* __restrict__ cnt, int* __restrict__ row_start)
{
    __shared__ int part[1024];
    const int t  = threadIdx.x;
    const int CH = (N_NODES + 1023) / 1024;      // 49
    const int lo = t * CH;
    const int hi = (lo + CH < N_NODES) ? lo + CH : N_NODES;

    int s = 0;
    for (int i = lo; i < hi; ++i) s += cnt[i];
    part[t] = s;
    __syncthreads();

    for (int off = 1; off < 1024; off <<= 1) {
        int v = (t >= off) ? part[t - off] : 0;
        __syncthreads();
        part[t] += v;
        __syncthreads();
    }

    int run = (t == 0) ? 0 : part[t - 1];
    for (int i = lo; i < hi; ++i) {
        row_start[i] = run;
        run += cnt[i];
        cnt[i] = 0;                               // becomes bucket cursor
    }
    if (t == 1023) row_start[N_NODES] = part[1023];
}

// ---------- kernel D: per-head sum of exp + bucket src ids by dst ----------
__global__ __launch_bounds__(256) void k_sum_bucket(
    const int* __restrict__ esrc, const int* __restrict__ edst,
    const float* __restrict__ s_src, const float* __restrict__ s_dst,
    const unsigned* __restrict__ gmax, double* __restrict__ gsum,
    const int* __restrict__ row_start, int* __restrict__ cursor,
    int* __restrict__ sorted_src)
{
    const float mx0 = fdec(gmax[0]);
    const float mx1 = fdec(gmax[1]);
    const float mx2 = fdec(gmax[2]);
    const float mx3 = fdec(gmax[3]);
    double a0 = 0.0, a1 = 0.0, a2 = 0.0, a3 = 0.0;
    const int stride = gridDim.x * blockDim.x;
    for (int e = blockIdx.x * blockDim.x + threadIdx.x; e < N_EDGES; e += stride) {
        int s = esrc[e], d = edst[e];
        int pos = row_start[d] + atomicAdd(&cursor[d], 1);
        sorted_src[pos] = s;
        float4 ss = *(const float4*)&s_src[s * HEADS];
        float4 sd = *(const float4*)&s_dst[d * HEADS];
        a0 += (double)expf(lrelu(ss.x + sd.x) - mx0);
        a1 += (double)expf(lrelu(ss.y + sd.y) - mx1);
        a2 += (double)expf(lrelu(ss.z + sd.z) - mx2);
        a3 += (double)expf(lrelu(ss.w + sd.w) - mx3);
    }
    #pragma unroll
    for (int m = 32; m >= 1; m >>= 1) {
        a0 += __shfl_xor(a0, m);
        a1 += __shfl_xor(a1, m);
        a2 += __shfl_xor(a2, m);
        a3 += __shfl_xor(a3, m);
    }
    if ((threadIdx.x & 63) == 0) {
        atomicAdd(&gsum[0], a0);
        atomicAdd(&gsum[1], a1);
        atomicAdd(&gsum[2], a2);
        atomicAdd(&gsum[3], a3);
    }
}

// ---------- kernel E: one wave per dst node, gather-reduce, no atomics ----------
__global__ __launch_bounds__(256) void k_agg(
    const int* __restrict__ row_start, const int* __restrict__ sorted_src,
    const float* __restrict__ h,
    const float* __restrict__ s_src, const float* __restrict__ s_dst,
    const unsigned* __restrict__ gmax, const double* __restrict__ gsum,
    float* __restrict__ out)
{
    const int wid = (int)((blockIdx.x * 256u + threadIdx.x) >> 6);   // node id
    if (wid >= N_NODES) return;
    const int lane = threadIdx.x & 63;
    const int head = lane >> 4;
    const int og   = (lane & 15) * 4;

    const int beg = row_start[wid];
    const int end = row_start[wid + 1];
    const float mx  = fdec(gmax[head]);
    const float inv = (float)(1.0 / gsum[head]);
    const float sd  = s_dst[wid * HEADS + head];

    float4 acc = make_float4(0.f, 0.f, 0.f, 0.f);

    int j = beg;
    for (; j + 1 < end; j += 2) {
        int s0 = sorted_src[j];
        int s1 = sorted_src[j + 1];
        float p0 = expf(lrelu(s_src[s0 * HEADS + head] + sd) - mx) * inv;
        float p1 = expf(lrelu(s_src[s1 * HEADS + head] + sd) - mx) * inv;
        float4 h0 = *(const float4*)&h[(size_t)s0 * HO + head * OUT_DIM + og];
        float4 h1 = *(const float4*)&h[(size_t)s1 * HO + head * OUT_DIM + og];
        acc.x = fmaf(p0, h0.x, acc.x); acc.y = fmaf(p0, h0.y, acc.y);
        acc.z = fmaf(p0, h0.z, acc.z); acc.w = fmaf(p0, h0.w, acc.w);
        acc.x = fmaf(p1, h1.x, acc.x); acc.y = fmaf(p1, h1.y, acc.y);
        acc.z = fmaf(p1, h1.z, acc.z); acc.w = fmaf(p1, h1.w, acc.w);
    }
    if (j < end) {
        int s0 = sorted_src[j];
        float p0 = expf(lrelu(s_src[s0 * HEADS + head] + sd) - mx) * inv;
        float4 h0 = *(const float4*)&h[(size_t)s0 * HO + head * OUT_DIM + og];
        acc.x = fmaf(p0, h0.x, acc.x); acc.y = fmaf(p0, h0.y, acc.y);
        acc.z = fmaf(p0, h0.z, acc.z); acc.w = fmaf(p0, h0.w, acc.w);
    }

    *(float4*)&out[(size_t)wid * HO + head * OUT_DIM + og] = acc;
}

// ---------- launch ----------
extern "C" void kernel_launch(void* const* d_in, const int* in_sizes, int n_in,
                              void* d_out, int out_size, void* d_ws, size_t ws_size,
                              hipStream_t stream)
{
    const float* x    = (const float*)d_in[0];
    const int*   eidx = (const int*)d_in[1];   // jax x64 off: int64 -> int32
    const float* W    = (const float*)d_in[2];
    const float* a    = (const float*)d_in[3];
    float* out = (float*)d_out;

    // workspace layout (bytes from d_ws base; base assumed >=8B aligned)
    float*    h      = (float*)d_ws;                                  // 12.8M floats
    float*    s_src  = h + (size_t)N_NODES * HO;                      // 200K floats
    float*    s_dst  = s_src + (size_t)N_NODES * HEADS;               // 200K floats
    double*   gsum   = (double*)(s_dst + (size_t)N_NODES * HEADS);    // 4 doubles (8B-aligned)
    unsigned* gmax   = (unsigned*)(gsum + 4);                         // 4 uints
    int*      row_start = (int*)(gmax + 4);                           // N_NODES+1 ints
    int*      cnt    = row_start + (N_NODES + 1);                     // N_NODES ints (hist/cursor)
    int*      sorted_src = cnt + N_NODES;                             // N_EDGES ints

    const int* esrc = eidx;
    const int* edst = eidx + N_EDGES;

    // zero: gsum(32B) + gmax(16B) contiguous; cnt
    hipMemsetAsync(gsum, 0, 4 * sizeof(double) + 4 * sizeof(unsigned), stream);
    hipMemsetAsync(cnt, 0, N_NODES * sizeof(int), stream);

    k_gemm<<<(N_NODES + NPB - 1) / NPB, 256, 0, stream>>>(x, W, a, h, s_src, s_dst);
    k_max_hist<<<1024, 256, 0, stream>>>(esrc, edst, s_src, s_dst, gmax, cnt);
    k_scan<<<1, 1024, 0, stream>>>(cnt, row_start);
    k_sum_bucket<<<1024, 256, 0, stream>>>(esrc, edst, s_src, s_dst, gmax, gsum,
                                           row_start, cnt, sorted_src);
    k_agg<<<(N_NODES * 64 + 255) / 256, 256, 0, stream>>>(row_start, sorted_src, h,
                                                          s_src, s_dst, gmax, gsum, out);
}

// Round 3
// 912.794 us; speedup vs baseline: 6.3180x; 1.0068x over previous
//
#include <hip/hip_runtime.h>
#include <stdint.h>

#define N_NODES 50000
#define N_EDGES 1600000
#define IN_DIM  128
#define OUT_DIM 64
#define HEADS   4
#define HO      (HEADS*OUT_DIM)   // 256

// ---------- helpers ----------
__device__ __forceinline__ unsigned fenc(float f) {
    unsigned u = __float_as_uint(f);
    return (u & 0x80000000u) ? ~u : (u | 0x80000000u);
}
__device__ __forceinline__ float fdec(unsigned u) {
    return __uint_as_float((u & 0x80000000u) ? (u ^ 0x80000000u) : ~u);
}
__device__ __forceinline__ float lrelu(float v) {
    return v >= 0.f ? v : 0.01f * v;
}

// ---------- kernel A: h = x @ W (per head), plus per-node scores ----------
#define NPW 8            // nodes per wave
#define WPB 4            // waves per block
#define NPB (NPW*WPB)    // 32 nodes per block

__global__ __launch_bounds__(256) void k_gemm(
    const float* __restrict__ x, const float* __restrict__ W,
    const float* __restrict__ a,
    float* __restrict__ h, float* __restrict__ s_src, float* __restrict__ s_dst)
{
    __shared__ float xs[NPB][IN_DIM];   // 16 KB
    const int tid  = threadIdx.x;
    const int wave = tid >> 6;
    const int lane = tid & 63;
    const int node0 = blockIdx.x * NPB;

    {
        float4* xsv = (float4*)&xs[0][0];
        const int ROW4 = IN_DIM / 4;            // 32
        const int total4 = NPB * ROW4;          // 1024
        for (int i = tid; i < total4; i += 256) {
            int row  = i / ROW4;
            int node = node0 + row;
            float4 v = make_float4(0.f, 0.f, 0.f, 0.f);
            if (node < N_NODES)
                v = ((const float4*)x)[(size_t)node * ROW4 + (i % ROW4)];
            xsv[i] = v;
        }
    }
    __syncthreads();

    const int head = lane >> 4;          // 0..3
    const int og   = (lane & 15) * 4;    // 0..60
    const int wn0  = wave * NPW;

    float4 acc[NPW];
    #pragma unroll
    for (int i = 0; i < NPW; ++i) acc[i] = make_float4(0.f, 0.f, 0.f, 0.f);

    const float* wp = &W[(size_t)(head * IN_DIM) * OUT_DIM + og];
    #pragma unroll 4
    for (int k = 0; k < IN_DIM; ++k) {
        float4 w4 = *(const float4*)(wp + (size_t)k * OUT_DIM);
        #pragma unroll
        for (int i = 0; i < NPW; ++i) {
            float xv = xs[wn0 + i][k];
            acc[i].x = fmaf(xv, w4.x, acc[i].x);
            acc[i].y = fmaf(xv, w4.y, acc[i].y);
            acc[i].z = fmaf(xv, w4.z, acc[i].z);
            acc[i].w = fmaf(xv, w4.w, acc[i].w);
        }
    }

    const float4 as = *(const float4*)&a[head * (2*OUT_DIM) + og];
    const float4 ad = *(const float4*)&a[head * (2*OUT_DIM) + OUT_DIM + og];

    #pragma unroll
    for (int i = 0; i < NPW; ++i) {
        int node = node0 + wn0 + i;
        if (node >= N_NODES) continue;
        *(float4*)&h[(size_t)node * HO + head * OUT_DIM + og] = acc[i];
        float ps = acc[i].x*as.x + acc[i].y*as.y + acc[i].z*as.z + acc[i].w*as.w;
        float pd = acc[i].x*ad.x + acc[i].y*ad.y + acc[i].z*ad.z + acc[i].w*ad.w;
        #pragma unroll
        for (int m = 8; m >= 1; m >>= 1) {
            ps += __shfl_xor(ps, m, 16);
            pd += __shfl_xor(pd, m, 16);
        }
        if ((lane & 15) == 0) {
            s_src[node * HEADS + head] = ps;
            s_dst[node * HEADS + head] = pd;
        }
    }
}

// ---------- kernel B: per-head global max + dst histogram ----------
__global__ __launch_bounds__(256) void k_max_hist(
    const int* __restrict__ esrc, const int* __restrict__ edst,
    const float* __restrict__ s_src, const float* __restrict__ s_dst,
    unsigned* __restrict__ gmax, int* __restrict__ cnt)
{
    float m0 = -1e30f, m1 = -1e30f, m2 = -1e30f, m3 = -1e30f;
    const int stride = gridDim.x * blockDim.x;
    for (int e = blockIdx.x * blockDim.x + threadIdx.x; e < N_EDGES; e += stride) {
        int s = esrc[e], d = edst[e];
        atomicAdd(&cnt[d], 1);
        float4 ss = *(const float4*)&s_src[s * HEADS];
        float4 sd = *(const float4*)&s_dst[d * HEADS];
        m0 = fmaxf(m0, lrelu(ss.x + sd.x));
        m1 = fmaxf(m1, lrelu(ss.y + sd.y));
        m2 = fmaxf(m2, lrelu(ss.z + sd.z));
        m3 = fmaxf(m3, lrelu(ss.w + sd.w));
    }
    #pragma unroll
    for (int m = 32; m >= 1; m >>= 1) {
        m0 = fmaxf(m0, __shfl_xor(m0, m));
        m1 = fmaxf(m1, __shfl_xor(m1, m));
        m2 = fmaxf(m2, __shfl_xor(m2, m));
        m3 = fmaxf(m3, __shfl_xor(m3, m));
    }
    if ((threadIdx.x & 63) == 0) {
        atomicMax(&gmax[0], fenc(m0));
        atomicMax(&gmax[1], fenc(m1));
        atomicMax(&gmax[2], fenc(m2));
        atomicMax(&gmax[3], fenc(m3));
    }
}

// ---------- kernel C: one-block exclusive scan of cnt -> row_start; zero cnt ----------
__global__ __launch_bounds__(1024) void k_scan(
    int* __restrict__ cnt, int* __restrict__ row_start)
{
    __shared__ int part[1024];
    const int t  = threadIdx.x;
    const int CH = (N_NODES + 1023) / 1024;      // 49
    const int lo = t * CH;
    const int hi = (lo + CH < N_NODES) ? lo + CH : N_NODES;

    int s = 0;
    for (int i = lo; i < hi; ++i) s += cnt[i];
    part[t] = s;
    __syncthreads();

    for (int off = 1; off < 1024; off <<= 1) {
        int v = (t >= off) ? part[t - off] : 0;
        __syncthreads();
        part[t] += v;
        __syncthreads();
    }

    int run = (t == 0) ? 0 : part[t - 1];
    for (int i = lo; i < hi; ++i) {
        row_start[i] = run;
        run += cnt[i];
        cnt[i] = 0;                               // becomes bucket cursor
    }
    if (t == 1023) row_start[N_NODES] = part[1023];
}

// ---------- kernel D: per-head sum of exp + bucket src ids by dst ----------
__global__ __launch_bounds__(256) void k_sum_bucket(
    const int* __restrict__ esrc, const int* __restrict__ edst,
    const float* __restrict__ s_src, const float* __restrict__ s_dst,
    const unsigned* __restrict__ gmax, double* __restrict__ gsum,
    const int* __restrict__ row_start, int* __restrict__ cursor,
    int* __restrict__ sorted_src)
{
    const float mx0 = fdec(gmax[0]);
    const float mx1 = fdec(gmax[1]);
    const float mx2 = fdec(gmax[2]);
    const float mx3 = fdec(gmax[3]);
    double a0 = 0.0, a1 = 0.0, a2 = 0.0, a3 = 0.0;
    const int stride = gridDim.x * blockDim.x;
    for (int e = blockIdx.x * blockDim.x + threadIdx.x; e < N_EDGES; e += stride) {
        int s = esrc[e], d = edst[e];
        int pos = row_start[d] + atomicAdd(&cursor[d], 1);
        sorted_src[pos] = s;
        float4 ss = *(const float4*)&s_src[s * HEADS];
        float4 sd = *(const float4*)&s_dst[d * HEADS];
        a0 += (double)expf(lrelu(ss.x + sd.x) - mx0);
        a1 += (double)expf(lrelu(ss.y + sd.y) - mx1);
        a2 += (double)expf(lrelu(ss.z + sd.z) - mx2);
        a3 += (double)expf(lrelu(ss.w + sd.w) - mx3);
    }
    #pragma unroll
    for (int m = 32; m >= 1; m >>= 1) {
        a0 += __shfl_xor(a0, m);
        a1 += __shfl_xor(a1, m);
        a2 += __shfl_xor(a2, m);
        a3 += __shfl_xor(a3, m);
    }
    if ((threadIdx.x & 63) == 0) {
        atomicAdd(&gsum[0], a0);
        atomicAdd(&gsum[1], a1);
        atomicAdd(&gsum[2], a2);
        atomicAdd(&gsum[3], a3);
    }
}

// ---------- kernel E: one wave per dst node, gather-reduce, no atomics ----------
__global__ __launch_bounds__(256) void k_agg(
    const int* __restrict__ row_start, const int* __restrict__ sorted_src,
    const float* __restrict__ h,
    const float* __restrict__ s_src, const float* __restrict__ s_dst,
    const unsigned* __restrict__ gmax, const double* __restrict__ gsum,
    float* __restrict__ out)
{
    const int wid = (int)((blockIdx.x * 256u + threadIdx.x) >> 6);   // node id
    if (wid >= N_NODES) return;
    const int lane = threadIdx.x & 63;
    const int head = lane >> 4;
    const int og   = (lane & 15) * 4;

    const int beg = row_start[wid];
    const int end = row_start[wid + 1];
    const float mx  = fdec(gmax[head]);
    const float inv = (float)(1.0 / gsum[head]);
    const float sd  = s_dst[wid * HEADS + head];

    float4 acc = make_float4(0.f, 0.f, 0.f, 0.f);

    int j = beg;
    for (; j + 1 < end; j += 2) {
        int s0 = sorted_src[j];
        int s1 = sorted_src[j + 1];
        float p0 = expf(lrelu(s_src[s0 * HEADS + head] + sd) - mx) * inv;
        float p1 = expf(lrelu(s_src[s1 * HEADS + head] + sd) - mx) * inv;
        float4 h0 = *(const float4*)&h[(size_t)s0 * HO + head * OUT_DIM + og];
        float4 h1 = *(const float4*)&h[(size_t)s1 * HO + head * OUT_DIM + og];
        acc.x = fmaf(p0, h0.x, acc.x); acc.y = fmaf(p0, h0.y, acc.y);
        acc.z = fmaf(p0, h0.z, acc.z); acc.w = fmaf(p0, h0.w, acc.w);
        acc.x = fmaf(p1, h1.x, acc.x); acc.y = fmaf(p1, h1.y, acc.y);
        acc.z = fmaf(p1, h1.z, acc.z); acc.w = fmaf(p1, h1.w, acc.w);
    }
    if (j < end) {
        int s0 = sorted_src[j];
        float p0 = expf(lrelu(s_src[s0 * HEADS + head] + sd) - mx) * inv;
        float4 h0 = *(const float4*)&h[(size_t)s0 * HO + head * OUT_DIM + og];
        acc.x = fmaf(p0, h0.x, acc.x); acc.y = fmaf(p0, h0.y, acc.y);
        acc.z = fmaf(p0, h0.z, acc.z); acc.w = fmaf(p0, h0.w, acc.w);
    }

    *(float4*)&out[(size_t)wid * HO + head * OUT_DIM + og] = acc;
}

// ---------- launch ----------
extern "C" void kernel_launch(void* const* d_in, const int* in_sizes, int n_in,
                              void* d_out, int out_size, void* d_ws, size_t ws_size,
                              hipStream_t stream)
{
    const float* x    = (const float*)d_in[0];
    const int*   eidx = (const int*)d_in[1];   // jax x64 off: int64 -> int32
    const float* W    = (const float*)d_in[2];
    const float* a    = (const float*)d_in[3];
    float* out = (float*)d_out;

    // workspace layout (bytes from d_ws base; base assumed >=8B aligned)
    float*    h      = (float*)d_ws;                                  // 12.8M floats
    float*    s_src  = h + (size_t)N_NODES * HO;                      // 200K floats
    float*    s_dst  = s_src + (size_t)N_NODES * HEADS;               // 200K floats
    double*   gsum   = (double*)(s_dst + (size_t)N_NODES * HEADS);    // 4 doubles (8B-aligned)
    unsigned* gmax   = (unsigned*)(gsum + 4);                         // 4 uints
    int*      row_start = (int*)(gmax + 4);                           // N_NODES+1 ints
    int*      cnt    = row_start + (N_NODES + 1);                     // N_NODES ints (hist/cursor)
    int*      sorted_src = cnt + N_NODES;                             // N_EDGES ints

    const int* esrc = eidx;
    const int* edst = eidx + N_EDGES;

    // zero: gsum(32B) + gmax(16B) contiguous; cnt
    hipMemsetAsync(gsum, 0, 4 * sizeof(double) + 4 * sizeof(unsigned), stream);
    hipMemsetAsync(cnt, 0, N_NODES * sizeof(int), stream);

    k_gemm<<<(N_NODES + NPB - 1) / NPB, 256, 0, stream>>>(x, W, a, h, s_src, s_dst);
    k_max_hist<<<1024, 256, 0, stream>>>(esrc, edst, s_src, s_dst, gmax, cnt);
    k_scan<<<1, 1024, 0, stream>>>(cnt, row_start);
    k_sum_bucket<<<1024, 256, 0, stream>>>(esrc, edst, s_src, s_dst, gmax, gsum,
                                           row_start, cnt, sorted_src);
    k_agg<<<(N_NODES * 64 + 255) / 256, 256, 0, stream>>>(row_start, sorted_src, h,
                                                          s_src, s_dst, gmax, gsum, out);
}